// Round 1
// baseline (1120.852 us; speedup 1.0000x reference)
//
#include <hip/hip_runtime.h>
#include <cstdint>

#define EPS_BN 1e-5f

typedef __attribute__((ext_vector_type(8))) short s16x8;
typedef __attribute__((ext_vector_type(4))) float f32x4;
typedef __attribute__((ext_vector_type(4))) unsigned int u32x4;

__device__ __forceinline__ float bf2f(short s){
  unsigned int u = ((unsigned int)(unsigned short)s) << 16;
  return __builtin_bit_cast(float, u);
}
__device__ __forceinline__ unsigned int cvtpk_bf16(float lo, float hi){
  unsigned int r;
  asm("v_cvt_pk_bf16_f32 %0, %1, %2" : "=v"(r) : "v"(lo), "v"(hi));
  return r;
}
__device__ __forceinline__ short f2bf(float f){
  return (short)(unsigned short)(cvtpk_bf16(f, f) & 0xffffu);
}

// ---------------- P0: feats f32 -> bf16 ----------------
__global__ __launch_bounds__(256) void cvt_feats(const float* __restrict__ in,
                                                 short* __restrict__ out, long nvec8){
  long t = (long)blockIdx.x * blockDim.x + threadIdx.x;
  long stride = (long)gridDim.x * blockDim.x;
  for (long v = t; v < nvec8; v += stride){
    const float4* p = (const float4*)in + 2*v;
    float4 a = p[0], b = p[1];
    u32x4 w;
    w[0] = cvtpk_bf16(a.x, a.y); w[1] = cvtpk_bf16(a.z, a.w);
    w[2] = cvtpk_bf16(b.x, b.y); w[3] = cvtpk_bf16(b.z, b.w);
    ((u32x4*)out)[v] = w;
  }
}

// ---------------- P1: pack W [9][64][64] f32 -> bf16 MFMA B-fragment order ----
// layout: frag[t in 0..18)[n in 0..4)[lane in 0..64)[j in 0..8)
//   cin = (t&1)*32 + (lane>>4)*8 + j, cout = n*16 + (lane&15), tap = t>>1
__global__ __launch_bounds__(256) void pack_w(const float* __restrict__ W1,
                                              const float* __restrict__ W2,
                                              short* __restrict__ W1F,
                                              short* __restrict__ W2F){
  int o = blockIdx.x * 256 + threadIdx.x;
  if (o >= 2*36864) return;
  const float* W = (o < 36864) ? W1 : W2;
  short* D = (o < 36864) ? W1F : W2F;
  int oo = o % 36864;
  int j = oo & 7;
  int l = (oo >> 3) & 63;
  int n = (oo >> 9) & 3;
  int t = oo >> 11;
  int tap = t >> 1, h = t & 1, g = l >> 4;
  int cin = h*32 + g*8 + j;
  int cout = n*16 + (l & 15);
  float v = W[((long)tap*64 + cin)*64 + cout];
  D[oo] = f2bf(v);
}

// ---------------- conv: Y[N,64] = sum_k gather(src,nbr[:,k]) @ W[k] ----------
// AFFINE: apply relu(x*scale+shift) to gathered bf16 values (conv2 path).
// Output: conv1 -> ybf (bf16), conv2 -> yf (f32).
template<bool AFFINE>
__global__ __launch_bounds__(256) void conv_mfma(const short* __restrict__ src,
                                                 const int* __restrict__ nbr,
                                                 const short* __restrict__ wfrag,
                                                 const float* __restrict__ scale,
                                                 const float* __restrict__ shiftv,
                                                 short* __restrict__ ybf,
                                                 float* __restrict__ yf,
                                                 int N){
  __shared__ short ldsW[36864]; // 72 KiB: 18 k-steps * 4 col-tiles * 64 lanes * 8 bf16
  const int tid = threadIdx.x;
  {
    const s16x8* gs = (const s16x8*)wfrag;
    s16x8* ls = (s16x8*)ldsW;
    #pragma unroll
    for (int i = 0; i < 18; ++i) ls[i*256 + tid] = gs[i*256 + tid];
  }
  const int lane = tid & 63;
  const int wave = tid >> 6;
  const int l15 = lane & 15;
  const int g = lane >> 4;
  const long rowbase = (long)blockIdx.x * 256 + wave * 64;

  float sc[2][8], sh[2][8];
  if (AFFINE){
    #pragma unroll
    for (int h = 0; h < 2; ++h)
      #pragma unroll
      for (int j = 0; j < 8; ++j){
        int ch = h*32 + g*8 + j;
        sc[h][j] = scale[ch];
        sh[h][j] = shiftv[ch];
      }
  }

  f32x4 acc[4][4];
  #pragma unroll
  for (int rt = 0; rt < 4; ++rt)
    #pragma unroll
    for (int n = 0; n < 4; ++n)
      acc[rt][n] = (f32x4){0.f, 0.f, 0.f, 0.f};

  __syncthreads();

  for (int tap = 0; tap < 9; ++tap){
    int idx[4];
    #pragma unroll
    for (int rt = 0; rt < 4; ++rt){
      long row = rowbase + rt*16 + l15;
      idx[rt] = (row < N) ? nbr[row*9 + tap] : 0;
    }
    s16x8 av[4][2];
    #pragma unroll
    for (int rt = 0; rt < 4; ++rt){
      const short* p = src + (long)idx[rt]*64 + g*8;
      av[rt][0] = *(const s16x8*)(p);
      av[rt][1] = *(const s16x8*)(p + 32);
    }
    if (AFFINE){
      #pragma unroll
      for (int rt = 0; rt < 4; ++rt)
        #pragma unroll
        for (int h = 0; h < 2; ++h){
          u32x4 w = __builtin_bit_cast(u32x4, av[rt][h]);
          #pragma unroll
          for (int jw = 0; jw < 4; ++jw){
            float f0 = __builtin_bit_cast(float, w[jw] << 16);
            float f1 = __builtin_bit_cast(float, w[jw] & 0xffff0000u);
            f0 = fmaxf(fmaf(f0, sc[h][2*jw],   sh[h][2*jw]),   0.f);
            f1 = fmaxf(fmaf(f1, sc[h][2*jw+1], sh[h][2*jw+1]), 0.f);
            w[jw] = cvtpk_bf16(f0, f1);
          }
          av[rt][h] = __builtin_bit_cast(s16x8, w);
        }
    }
    #pragma unroll
    for (int h = 0; h < 2; ++h){
      const int t = tap*2 + h;
      s16x8 bv[4];
      #pragma unroll
      for (int n = 0; n < 4; ++n)
        bv[n] = *(const s16x8*)&ldsW[((t*4 + n)*64 + lane)*8];
      #pragma unroll
      for (int rt = 0; rt < 4; ++rt)
        #pragma unroll
        for (int n = 0; n < 4; ++n)
          acc[rt][n] = __builtin_amdgcn_mfma_f32_16x16x32_bf16(av[rt][h], bv[n], acc[rt][n], 0, 0, 0);
    }
  }

  // epilogue: D element (row = rowbase + rt*16 + g*4 + r, col = n*16 + l15)
  #pragma unroll
  for (int rt = 0; rt < 4; ++rt){
    #pragma unroll
    for (int r = 0; r < 4; ++r){
      long row = rowbase + rt*16 + g*4 + r;
      if (row < N){
        if (!AFFINE){
          short* dst = ybf + row*64 + l15;
          dst[0]  = f2bf(acc[rt][0][r]);
          dst[16] = f2bf(acc[rt][1][r]);
          dst[32] = f2bf(acc[rt][2][r]);
          dst[48] = f2bf(acc[rt][3][r]);
        } else {
          float* dst = yf + row*64 + l15;
          dst[0]  = acc[rt][0][r];
          dst[16] = acc[rt][1][r];
          dst[32] = acc[rt][2][r];
          dst[48] = acc[rt][3][r];
        }
      }
    }
  }
}

// ---------------- stats over bf16 [N][64]: per-block partial sum/sumsq -------
__global__ __launch_bounds__(256) void stats_bf16(const short* __restrict__ y,
                                                  float* __restrict__ part, long nvec8){
  long t = (long)blockIdx.x * 256 + threadIdx.x;
  long stride = (long)gridDim.x * 256;
  float s[8] = {0,0,0,0,0,0,0,0}, q[8] = {0,0,0,0,0,0,0,0};
  for (long v = t; v < nvec8; v += stride){
    s16x8 d = ((const s16x8*)y)[v];
    #pragma unroll
    for (int j = 0; j < 8; ++j){
      float f = bf2f(d[j]);
      s[j] += f; q[j] += f*f;
    }
  }
  __shared__ float rs[64], rq[64];
  if (threadIdx.x < 64){ rs[threadIdx.x] = 0.f; rq[threadIdx.x] = 0.f; }
  __syncthreads();
  int cb = (threadIdx.x & 7) * 8;
  #pragma unroll
  for (int j = 0; j < 8; ++j){
    atomicAdd(&rs[cb + j], s[j]);
    atomicAdd(&rq[cb + j], q[j]);
  }
  __syncthreads();
  if (threadIdx.x < 64){
    part[(long)blockIdx.x*64 + threadIdx.x] = rs[threadIdx.x];
    part[((long)gridDim.x + blockIdx.x)*64 + threadIdx.x] = rq[threadIdx.x];
  }
}

// ---------------- stats over f32 [N][64] -------------------------------------
__global__ __launch_bounds__(256) void stats_f32(const float* __restrict__ y,
                                                 float* __restrict__ part, long nvec4){
  long t = (long)blockIdx.x * 256 + threadIdx.x;
  long stride = (long)gridDim.x * 256;
  float s[4] = {0,0,0,0}, q[4] = {0,0,0,0};
  for (long v = t; v < nvec4; v += stride){
    float4 d = ((const float4*)y)[v];
    s[0] += d.x; q[0] += d.x*d.x;
    s[1] += d.y; q[1] += d.y*d.y;
    s[2] += d.z; q[2] += d.z*d.z;
    s[3] += d.w; q[3] += d.w*d.w;
  }
  __shared__ float rs[64], rq[64];
  if (threadIdx.x < 64){ rs[threadIdx.x] = 0.f; rq[threadIdx.x] = 0.f; }
  __syncthreads();
  int cb = (threadIdx.x & 15) * 4;
  #pragma unroll
  for (int j = 0; j < 4; ++j){
    atomicAdd(&rs[cb + j], s[j]);
    atomicAdd(&rq[cb + j], q[j]);
  }
  __syncthreads();
  if (threadIdx.x < 64){
    part[(long)blockIdx.x*64 + threadIdx.x] = rs[threadIdx.x];
    part[((long)gridDim.x + blockIdx.x)*64 + threadIdx.x] = rq[threadIdx.x];
  }
}

// ---------------- finalize BN affine: scale = g*rstd, shift = b - mean*scale -
__global__ void finalize_bn(const float* __restrict__ part, int nb,
                            const float* __restrict__ gamma,
                            const float* __restrict__ beta, float invN,
                            float* __restrict__ scale, float* __restrict__ shiftv){
  int c = threadIdx.x;
  if (c >= 64) return;
  float s = 0.f, q = 0.f;
  for (int b = 0; b < nb; ++b){
    s += part[(long)b*64 + c];
    q += part[((long)nb + b)*64 + c];
  }
  float mean = s * invN;
  float var = q * invN - mean*mean;
  float sc = gamma[c] * rsqrtf(var + EPS_BN);
  scale[c] = sc;
  shiftv[c] = beta[c] - mean*sc;
}

// ---------------- final: out = relu(y2*scale2+shift2 + feats), in place ------
__global__ __launch_bounds__(256) void final_out(float* __restrict__ y,
                                                 const float* __restrict__ feats,
                                                 const float* __restrict__ scale,
                                                 const float* __restrict__ shiftv,
                                                 long nvec4){
  long t = (long)blockIdx.x * blockDim.x + threadIdx.x;
  long stride = (long)gridDim.x * blockDim.x;  // multiple of 16 -> channel-stable
  int cb = ((int)(t & 15)) * 4;
  float s0 = scale[cb], s1 = scale[cb+1], s2 = scale[cb+2], s3 = scale[cb+3];
  float h0 = shiftv[cb], h1 = shiftv[cb+1], h2 = shiftv[cb+2], h3 = shiftv[cb+3];
  for (long v = t; v < nvec4; v += stride){
    float4 a = ((const float4*)y)[v];
    float4 f = ((const float4*)feats)[v];
    float4 r;
    r.x = fmaxf(fmaf(a.x, s0, h0) + f.x, 0.f);
    r.y = fmaxf(fmaf(a.y, s1, h1) + f.y, 0.f);
    r.z = fmaxf(fmaf(a.z, s2, h2) + f.z, 0.f);
    r.w = fmaxf(fmaf(a.w, s3, h3) + f.w, 0.f);
    ((float4*)y)[v] = r;
  }
}

extern "C" void kernel_launch(void* const* d_in, const int* in_sizes, int n_in,
                              void* d_out, int out_size, void* d_ws, size_t ws_size,
                              hipStream_t stream){
  const float* feats = (const float*)d_in[0];
  const float* W1    = (const float*)d_in[1];
  const float* g1    = (const float*)d_in[2];
  const float* b1    = (const float*)d_in[3];
  const float* W2    = (const float*)d_in[4];
  const float* g2    = (const float*)d_in[5];
  const float* b2    = (const float*)d_in[6];
  const int*   nbr1  = (const int*)d_in[7];
  const int*   nbr2  = (const int*)d_in[8];
  float* out = (float*)d_out;

  const int  N  = in_sizes[0] / 64;
  const long NC = (long)N * 64;

  // workspace layout
  char* ws = (char*)d_ws;
  short* F16 = (short*)ws;                 // NC bf16 (feats)
  short* Y1  = (short*)(ws + NC*2);        // NC bf16 (conv1 raw out)
  char* tail = ws + NC*4;
  short* W1F = (short*)tail;               // 36864 bf16
  short* W2F = W1F + 36864;                // 36864 bf16
  float* scale1 = (float*)(tail + 4*36864);
  float* shift1 = scale1 + 64;
  float* scale2 = shift1 + 64;
  float* shift2 = scale2 + 64;
  float* part   = shift2 + 64;             // 2 * SB * 64 floats (reused)

  const long nvec8 = NC / 8;
  const long nvec4 = NC / 4;
  const int  nblk  = (N + 255) / 256;
  const int  SB    = 512;
  const float invN = 1.0f / (float)N;

  cvt_feats<<<2048, 256, 0, stream>>>(feats, F16, nvec8);
  pack_w<<<288, 256, 0, stream>>>(W1, W2, W1F, W2F);

  conv_mfma<false><<<nblk, 256, 0, stream>>>(F16, nbr1, W1F, nullptr, nullptr, Y1, nullptr, N);

  stats_bf16<<<SB, 256, 0, stream>>>(Y1, part, nvec8);
  finalize_bn<<<1, 64, 0, stream>>>(part, SB, g1, b1, invN, scale1, shift1);

  conv_mfma<true><<<nblk, 256, 0, stream>>>(Y1, nbr2, W2F, scale1, shift1, nullptr, out, N);

  stats_f32<<<SB, 256, 0, stream>>>(out, part, nvec4);
  finalize_bn<<<1, 64, 0, stream>>>(part, SB, g2, b2, invN, scale2, shift2);

  final_out<<<2048, 256, 0, stream>>>(out, feats, scale2, shift2, nvec4);
}